// Round 2
// 193.251 us; speedup vs baseline: 1.0159x; 1.0159x over previous
//
#include <hip/hip_runtime.h>
#include <math.h>

#define NC 80
#define TOPKK 10
#define EPSF 1e-9f
#define IOU_EPSF 1e-7f
#define NA 8400
#define NGMAX 64

typedef float f4nt __attribute__((ext_vector_type(4)));

// IoU exactly as reference: inter/(a1+a2-inter+eps)
__device__ __forceinline__ float iou_xyxy(float px0, float py0, float px1, float py1,
                                          float parea,
                                          float gx0, float gy0, float gx1, float gy1,
                                          float garea) {
    float iw = fmaxf(fminf(px1, gx1) - fmaxf(px0, gx0), 0.0f);
    float ih = fmaxf(fminf(py1, gy1) - fmaxf(py0, gy0), 0.0f);
    float inter = iw * ih;
    return inter / (parea + garea - inter + IOU_EPSF);
}

__device__ __forceinline__ float align_metric(float s, float ov) {
    float ov2 = ov * ov;
    return sqrtf(s) * (ov2 * ov2 * ov2);
}

// sorted-insert into the per-lane descending top-10 list (ties: earlier entry
// = lower anchor idx stays ahead, matching jax.lax.top_k value-desc/idx-asc)
#define TK_INSERT(vv, aa) do {                                              \
    float nv[TOPKK]; int ni[TOPKK];                                         \
    _Pragma("unroll")                                                       \
    for (int q = 0; q < TOPKK; ++q) {                                       \
        bool keep = (lv[q] >= (vv));                                        \
        bool atp  = (q == 0) ? !keep : (!keep && (lv[q - 1] >= (vv)));      \
        nv[q] = keep ? lv[q] : (atp ? (vv) : lv[q - 1]);                    \
        ni[q] = keep ? li[q] : (atp ? (aa) : li[q - 1]);                    \
    }                                                                       \
    _Pragma("unroll")                                                       \
    for (int q = 0; q < TOPKK; ++q) { lv[q] = nv[q]; li[q] = ni[q]; }       \
} while (0)

// process the pipelined (previous) candidate: IoU + metric + insert
#define TK_PROCESS() do {                                                   \
    float parea_ = (pb_p.z - pb_p.x) * (pb_p.w - pb_p.y);                   \
    float ov_ = iou_xyxy(pb_p.x, pb_p.y, pb_p.z, pb_p.w, parea_,            \
                         gb.x, gb.y, gb.z, gb.w, garea);                    \
    float v_ = align_metric(sc_p, ov_);                                     \
    if (v_ > 0.0f && v_ > lv[TOPKK - 1]) TK_INSERT(v_, a_p);                \
} while (0)

// Top-k, rect-restricted: one 64-lane wave per (b,g); 4 waves/block; no LDS.
// Compact top-10 anchor-index list per (b,g). Order/tiebreak = jax.lax.top_k
// via key (v_bits<<32)|~idx. Zero-fill = lowest-index zero-valued anchors.
// R8: runtime int-div replaced by exact float-recip (+1-step correction);
//     2-stage software pipeline on the pd_bboxes/pd_scores gathers.
__global__ __launch_bounds__(256) void topk_rect_kernel(
    const float* __restrict__ pd_scores, const float* __restrict__ pd_bboxes,
    const int* __restrict__ gt_labels, const float* __restrict__ gt_bboxes,
    const int* __restrict__ mask_gt,
    int* __restrict__ idx_out, int ng, int total_bg)
{
    int lin = blockIdx.x * 4 + (threadIdx.x >> 6);
    if (lin >= total_bg) return;
    int b = lin / ng;
    int g = lin - b * ng;
    int lane = threadIdx.x & 63;
    int* __restrict__ slot = idx_out + (long)lin * TOPKK;

    if (mask_gt[b * ng + g] == 0) {          // invalid gt: sentinel list
        if (lane < TOPKK) slot[lane] = -1;
        return;
    }

    int lab = gt_labels[b * ng + g];
    float4 gb = ((const float4*)gt_bboxes)[b * ng + g];
    float garea = (gb.z - gb.x) * (gb.w - gb.y);
    const float* __restrict__ srow = pd_scores + ((long)b * NA) * NC + lab;
    const float4* __restrict__ pbb = (const float4*)(pd_bboxes + (long)b * NA * 4);

    // per-level candidate rectangles (superset; exact test inside loop)
    const int ls[3] = {8, 16, 32};
    const int ln[3] = {80, 40, 20};
    const int lb[3] = {0, 6400, 8000};
    int jlo[3], ilo[3], rw[3], cnt[3];
    float inv_rw[3];
    int tot = 0;
#pragma unroll
    for (int l = 0; l < 3; ++l) {
        float s = (float)ls[l];
        int j0 = (int)floorf(gb.x / s - 0.5f) - 1; if (j0 < 0) j0 = 0;
        int j1 = (int)ceilf (gb.z / s - 0.5f) + 1; if (j1 > ln[l] - 1) j1 = ln[l] - 1;
        int i0 = (int)floorf(gb.y / s - 0.5f) - 1; if (i0 < 0) i0 = 0;
        int i1 = (int)ceilf (gb.w / s - 0.5f) + 1; if (i1 > ln[l] - 1) i1 = ln[l] - 1;
        int w = j1 - j0 + 1; if (w < 0) w = 0;
        int h = i1 - i0 + 1; if (h < 0) h = 0;
        jlo[l] = j0; ilo[l] = i0; rw[l] = w; cnt[l] = w * h; tot += cnt[l];
        inv_rw[l] = (w > 0) ? 1.0f / (float)w : 0.0f;
    }

    float lv[TOPKK]; int li[TOPKK];
#pragma unroll
    for (int j = 0; j < TOPKK; ++j) { lv[j] = -1.0f; li[j] = -1; }

    // 2-stage pipelined scan: t ascending per lane => anchor idx ascending,
    // so per-lane insertion order (and thus tiebreak semantics) is unchanged.
    int a_p = 0; bool ok_p = false; float sc_p = 0.0f;
    float4 pb_p = make_float4(0.f, 0.f, 0.f, 0.f);
    for (int t = lane; t < tot; t += 64) {
        int l = 0, r = t;
        if (r >= cnt[0]) { r -= cnt[0]; l = 1; }
        if (l == 1 && r >= cnt[1]) { r -= cnt[1]; l = 2; }
        // exact div: r < ~1000, rw <= 83 -> float recip + 1-step correction
        int i = (int)((float)r * inv_rw[l]);
        int j = r - i * rw[l];
        if (j < 0) { --i; j += rw[l]; }
        else if (j >= rw[l]) { ++i; j -= rw[l]; }
        int ii = ilo[l] + i, jj = jlo[l] + j;
        int a  = lb[l] + ii * ln[l] + jj;
        float s  = (float)ls[l];
        float ax = (jj + 0.5f) * s, ay = (ii + 0.5f) * s;
        float d0 = ax - gb.x, d1 = ay - gb.y, d2 = gb.z - ax, d3 = gb.w - ay;
        float dmin = fminf(fminf(d0, d1), fminf(d2, d3));
        bool ok = dmin > EPSF;
        float4 pb = pb_p; float sc = 0.0f;
        if (ok) {                      // issue this iteration's gathers
            pb = pbb[a];
            sc = srow[(long)a * NC];
        }
        if (ok_p) TK_PROCESS();        // consume previous iteration's data
        a_p = a; pb_p = pb; sc_p = sc; ok_p = ok;
    }
    if (ok_p) TK_PROCESS();            // drain pipeline

    int m = 0;
    for (int it = 0; it < TOPKK; ++it) {
        unsigned long long myk = (lv[0] > 0.0f)
            ? (((unsigned long long)__float_as_uint(lv[0]) << 32)
               | (unsigned)(~(unsigned)li[0]))
            : 0ull;
        unsigned long long k = myk;
#pragma unroll
        for (int off = 32; off > 0; off >>= 1) {
            unsigned long long o = __shfl_xor(k, off, 64);
            k = (o > k) ? o : k;
        }
        if (k == 0ull) break;     // all positives drained (wave-uniform)
        if (myk == k) {           // unique owner records + pops
            slot[it] = li[0];
#pragma unroll
            for (int q = 0; q < TOPKK - 1; ++q) { lv[q] = lv[q + 1]; li[q] = li[q + 1]; }
            lv[TOPKK - 1] = -1.0f; li[TOPKK - 1] = -1;
        }
        m++;
    }

    // zero-fill slots m..9: lowest-index zero-valued anchors (recompute; skip
    // positives = already emitted). Guaranteed to find 10-m (NA-m >= need).
    if (m < TOPKK && lane == 0) {
        int p = m;
        for (int a = 0; p < TOPKK && a < NA; ++a) {
            int l  = (a < 6400) ? 0 : ((a < 8000) ? 1 : 2);
            int rr = a - lb[l];
            int ii = rr / ln[l];
            int jj = rr - ii * ln[l];
            float s  = (float)ls[l];
            float ax = (jj + 0.5f) * s, ay = (ii + 0.5f) * s;
            float d0 = ax - gb.x, d1 = ay - gb.y, d2 = gb.z - ax, d3 = gb.w - ay;
            float dmin = fminf(fminf(d0, d1), fminf(d2, d3));
            bool positive = false;
            if (dmin > EPSF) {
                float4 pb = pbb[a];
                float parea = (pb.z - pb.x) * (pb.w - pb.y);
                float ov = iou_xyxy(pb.x, pb.y, pb.z, pb.w, parea,
                                    gb.x, gb.y, gb.z, gb.w, garea);
                float sc = srow[(long)a * NC];
                positive = (align_metric(sc, ov) > 0.0f);
            }
            if (!positive) slot[p++] = a;   // zero-valued: in reference topk
        }
    }
}

// Fused assign + scores. Rebuilds the per-anchor g-bitmask in LDS from the
// compact index lists, then: w==0 fast path or filtered g-loop.
// R8: gts prefiltered by the block's anchor-center y-band. EXACT: the mask
// test is (anchor center strictly inside gt box); a gt with gb.y >= ymax or
// gb.w <= ymin fails that test for every anchor in this block, so it
// contributes 0 to every max and can never win any argmax (strict >).
__global__ __launch_bounds__(256) void assign_scores_kernel(
    const float* __restrict__ pd_scores, const float* __restrict__ pd_bboxes,
    const float* __restrict__ anc, const int* __restrict__ gt_labels,
    const float* __restrict__ gt_bboxes, const int* __restrict__ mask_gt,
    const int* __restrict__ idx_in,
    float* __restrict__ out_labels, float* __restrict__ out_bboxes,
    float* __restrict__ out_scores, float* __restrict__ out_fg,
    float* __restrict__ out_tgt, int ng, int blocksPerB)
{
    __shared__ float4 sgt[NGMAX];     // band-filtered gts, original order
    __shared__ float  sarea[NGMAX];
    __shared__ int    slab[NGMAX];
    __shared__ int    sgi[NGMAX];     // original g index of filtered entry
    __shared__ int    snf;            // filtered count
    __shared__ float4 sgt0;           // original gt 0 (defaults; always valid)
    __shared__ int    slab0s;
    __shared__ unsigned long long smask[256];
    __shared__ int    plab[256];
    __shared__ float  pt[256];

    int b  = blockIdx.x / blocksPerB;
    int a0 = (blockIdx.x - b * blocksPerB) * 256;
    int a  = a0 + threadIdx.x;

    smask[threadIdx.x] = 0ull;

    // ---- block anchor-center y-band (wave-uniform arithmetic) ----
    const int Lb[3] = {0, 6400, 8000};
    const int Lc[3] = {6400, 1600, 400};
    const int Ln[3] = {80, 40, 20};
    const int Ls[3] = {8, 16, 32};
    float ymin = 1e30f, ymax = -1e30f;
    {
        int aend = a0 + 255; if (aend > NA - 1) aend = NA - 1;
#pragma unroll
        for (int l = 0; l < 3; ++l) {
            int as_ = a0   > Lb[l]             ? a0   : Lb[l];
            int ae_ = aend < Lb[l] + Lc[l] - 1 ? aend : Lb[l] + Lc[l] - 1;
            if (as_ <= ae_) {
                int r0 = (as_ - Lb[l]) / Ln[l];   // compile-time divisors
                int r1 = (ae_ - Lb[l]) / Ln[l];
                float s = (float)Ls[l];
                ymin = fminf(ymin, (r0 + 0.5f) * s);
                ymax = fmaxf(ymax, (r1 + 0.5f) * s);
            }
        }
    }

    // ---- wave-0 ordered compaction of band-overlapping valid gts ----
    if (threadIdx.x < 64) {
        int g = threadIdx.x;
        bool ok = false;
        float4 gb = make_float4(0.f, 0.f, 0.f, 0.f);
        if (g < ng && mask_gt[b * ng + g] != 0) {
            gb = ((const float4*)gt_bboxes)[b * ng + g];
            ok = (gb.y < ymax) && (gb.w > ymin);   // conservative, exact
        }
        unsigned long long bal = __ballot(ok);
        int pos = __popcll(bal & ((1ull << g) - 1ull));
        if (ok) {
            sgt[pos]   = gb;
            sarea[pos] = (gb.z - gb.x) * (gb.w - gb.y);
            slab[pos]  = gt_labels[b * ng + g];
            sgi[pos]   = g;
        }
        if (g == 0) {
            snf    = __popcll(bal);
            sgt0   = ((const float4*)gt_bboxes)[b * ng];
            slab0s = gt_labels[b * ng];
        }
    }
    __syncthreads();

    // build bitmask for this block's anchors from the compact lists
    {
        int nent = ng * TOPKK;                        // 640
        const int* lst = idx_in + (long)b * nent;
        for (int i = threadIdx.x; i < nent; i += 256) {
            int aa = lst[i];
            unsigned off = (unsigned)(aa - a0);
            if (aa >= 0 && off < 256u) {
                atomicOr(&smask[off], 1ull << (i / TOPKK));   // g = i/10
            }
        }
    }
    __syncthreads();

    bool alive = (a < NA);
    int labi0 = slab0s < 0 ? 0 : slab0s;
    int labi = labi0; float t = 0.0f;

    if (alive) {
        long ba = (long)b * NA + a;
        unsigned long long w = smask[threadIdx.x];
        if (w == 0ull) {
            // fg=0, tgt=argmax(zeros)=0: defaults, exact per reference algebra
            __builtin_nontemporal_store((float)labi0, &out_labels[ba]);
            f4nt g0; g0.x = sgt0.x; g0.y = sgt0.y; g0.z = sgt0.z; g0.w = sgt0.w;
            __builtin_nontemporal_store(g0, &((f4nt*)out_bboxes)[ba]);
            __builtin_nontemporal_store(0.0f, &out_fg[ba]);
            __builtin_nontemporal_store(0.0f, &out_tgt[ba]);
        } else {
            float ax = anc[a * 2 + 0];
            float ay = anc[a * 2 + 1];
            float4 pb = ((const float4*)pd_bboxes)[ba];
            float parea = (pb.z - pb.x) * (pb.w - pb.y);
            const float* __restrict__ srow = pd_scores + ba * NC;

            int cnt = 0, pos_k = 0, best_k = 0;
            float best_ov = 0.0f;
            float m_align = 0.0f, m_ov = 0.0f, t_raw = 0.0f;
            int nf = snf;

            for (int k = 0; k < nf; ++k) {
                float4 gbk = sgt[k];
                float d0 = ax - gbk.x, d1 = ay - gbk.y;
                float d2 = gbk.z - ax, d3 = gbk.w - ay;
                float dmin = fminf(fminf(d0, d1), fminf(d2, d3));
                bool mask = (dmin > EPSF);
                float ov = 0.0f, al = 0.0f;
                if (mask) {
                    ov = iou_xyxy(pb.x, pb.y, pb.z, pb.w, parea,
                                  gbk.x, gbk.y, gbk.z, gbk.w, sarea[k]);
                    float sc = srow[slab[k]];
                    al = align_metric(sc, ov);
                }
                bool pos = mask && ((w >> sgi[k]) & 1ull);
                if (pos) { if (cnt == 0) pos_k = k; cnt++; }
                if (ov > best_ov) { best_ov = ov; best_k = k; }  // first max wins
                m_align = fmaxf(m_align, al);
                m_ov    = fmaxf(m_ov, ov);
                t_raw   = fmaxf(t_raw, al * ov);
            }

            if (cnt == 0) {
                // unreachable by construction (w bit => in-box, in-band, valid)
                // but keep the exact-default path for safety
                __builtin_nontemporal_store((float)labi0, &out_labels[ba]);
                f4nt g0; g0.x = sgt0.x; g0.y = sgt0.y; g0.z = sgt0.z; g0.w = sgt0.w;
                __builtin_nontemporal_store(g0, &((f4nt*)out_bboxes)[ba]);
                __builtin_nontemporal_store(0.0f, &out_fg[ba]);
                __builtin_nontemporal_store(0.0f, &out_tgt[ba]);
            } else {
                int tk = (cnt > 1) ? best_k : pos_k;
                labi = slab[tk]; if (labi < 0) labi = 0;
                __builtin_nontemporal_store((float)labi, &out_labels[ba]);
                float4 tb = sgt[tk];
                f4nt tb4; tb4.x = tb.x; tb4.y = tb.y; tb4.z = tb.z; tb4.w = tb.w;
                __builtin_nontemporal_store(tb4, &((f4nt*)out_bboxes)[ba]);
                __builtin_nontemporal_store(1.0f, &out_fg[ba]);
                __builtin_nontemporal_store((float)sgi[tk], &out_tgt[ba]);
                float na_ = fmaxf(m_align, EPSF);
                float no_ = fmaxf(m_ov, EPSF);
                t = (t_raw / na_) / no_;
            }
        }
    }

    plab[threadIdx.x] = labi;
    pt[threadIdx.x]   = t;
    __syncthreads();

    int cnt_rows = NA - a0; if (cnt_rows > 256) cnt_rows = 256;
    int tot4 = cnt_rows * (NC / 4);
    f4nt* __restrict__ oslab = (f4nt*)(out_scores + ((long)b * NA + a0) * NC);
    for (int i = threadIdx.x; i < tot4; i += 256) {
        int al = i / (NC / 4);
        int cg = (i - al * (NC / 4)) * 4;
        int lab = plab[al];
        float tv = pt[al];
        f4nt o;
        o.x = (cg     == lab) ? tv : 0.0f;
        o.y = (cg + 1 == lab) ? tv : 0.0f;
        o.z = (cg + 2 == lab) ? tv : 0.0f;
        o.w = (cg + 3 == lab) ? tv : 0.0f;
        __builtin_nontemporal_store(o, &oslab[i]);
    }
}

extern "C" void kernel_launch(void* const* d_in, const int* in_sizes, int n_in,
                              void* d_out, int out_size, void* d_ws, size_t ws_size,
                              hipStream_t stream) {
    const float* pd_scores = (const float*)d_in[0];
    const float* pd_bboxes = (const float*)d_in[1];
    const float* anc       = (const float*)d_in[2];
    const int*   gt_labels = (const int*)d_in[3];
    const float* gt_bboxes = (const float*)d_in[4];
    const int*   mask_gt   = (const int*)d_in[5];

    int na = in_sizes[2] / 2;            // 8400
    int bs = in_sizes[0] / (na * NC);    // 32
    int ng = in_sizes[3] / bs;           // 64

    long nBA = (long)bs * na;
    float* out        = (float*)d_out;
    float* out_labels = out;                 // bs*na
    float* out_bboxes = out + nBA;           // bs*na*4
    float* out_scores = out + nBA * 5;       // bs*na*80
    float* out_fg     = out + nBA * 85;      // bs*na
    float* out_tgt    = out + nBA * 86;      // bs*na

    int* idx = (int*)d_ws;                   // bs*ng*10 ints ≈ 82 KB, no memset

    int total_bg = bs * ng;
    int nblk = (total_bg + 3) / 4;   // 4 waves (b,g) per 256-thread block
    topk_rect_kernel<<<nblk, 256, 0, stream>>>(
        pd_scores, pd_bboxes, gt_labels, gt_bboxes, mask_gt, idx, ng, total_bg);

    int bpb = (na + 255) / 256;
    assign_scores_kernel<<<bs * bpb, 256, 0, stream>>>(
        pd_scores, pd_bboxes, anc, gt_labels, gt_bboxes, mask_gt, idx,
        out_labels, out_bboxes, out_scores, out_fg, out_tgt, ng, bpb);
}